// Round 3
// baseline (1002.355 us; speedup 1.0000x reference)
//
#include <hip/hip_runtime.h>
#include <hip/hip_bf16.h>

#define N_TOK 8192
#define DIM   1024
#define HID   4096
#define NEXP  8
#define TOPK  2
#define M_TOT (N_TOK*TOPK)

typedef __bf16 bf16x8 __attribute__((ext_vector_type(8)));
typedef float  f32x4  __attribute__((ext_vector_type(4)));

__device__ __forceinline__ unsigned short f2bf(float f) {
    union { __hip_bfloat16 h; unsigned short u; } c;
    c.h = __float2bfloat16(f);
    return c.u;
}

// async global->LDS, 16B/lane. LDS dest wave-uniform base; lane l lands at base + l*16B.
__device__ __forceinline__ void gload16(const unsigned short* g, unsigned short* l) {
    __builtin_amdgcn_global_load_lds(
        (const __attribute__((address_space(1))) void*)g,
        (__attribute__((address_space(3))) void*)l,
        16, 0, 0);
}

#define SBAR  __builtin_amdgcn_sched_barrier(0)
#define HWBAR asm volatile("s_barrier" ::: "memory")
#define LGKM0 asm volatile("s_waitcnt lgkmcnt(0)" ::: "memory")
#define VMC4  asm volatile("s_waitcnt vmcnt(4)" ::: "memory")

// ---------------------------------------------------------------------------
// 8-phase K-loop, 256x256 tile, BK=64, 8 waves (2M x 4N), dbuf LDS (128 KiB).
// Swizzle: within each row, 16B granule g stored at slot g ^ (row & 7).
// Stage schedule/iter: ph1,2: t1.B  ph3,4: t2.A  ph5,6: t2.B  ph7,8: t3.A.
// vmcnt(4) at phases 4 and 8 only (counted, never 0 in-loop).
// ---------------------------------------------------------------------------
template<int NT>
__device__ __forceinline__ void kloop8(
    unsigned short* As, unsigned short* Bs,
    const unsigned short* aP00, const unsigned short* aP01,
    const unsigned short* aP10, const unsigned short* aP11,
    const unsigned short* bP00, const unsigned short* bP01,
    const unsigned short* bP10, const unsigned short* bP11,
    int wofs, int rowA, int rowB, int g0, int g1,
    f32x4 (&acc)[8][4])
{
    constexpr int BUF = 16384;   // elements per (A or B) buffer
    bf16x8 A0[8], A1[8], Bf0[4], Bf1[4];

    // ---- prologue: stage t0 (A+B) and t1 (A only) ----
    gload16(aP00, &As[wofs]);
    gload16(aP01, &As[4096 + wofs]);
    gload16(aP10, &As[8192 + wofs]);
    gload16(aP11, &As[12288 + wofs]);
    gload16(bP00, &Bs[wofs]);
    gload16(bP01, &Bs[4096 + wofs]);
    gload16(bP10, &Bs[8192 + wofs]);
    gload16(bP11, &Bs[12288 + wofs]);
    gload16(aP00 + 64, &As[BUF + wofs]);
    gload16(aP01 + 64, &As[BUF + 4096 + wofs]);
    gload16(aP10 + 64, &As[BUF + 8192 + wofs]);
    gload16(aP11 + 64, &As[BUF + 12288 + wofs]);
    VMC4; SBAR; HWBAR; SBAR;

    for (int i = 0; i < NT/2; ++i) {
        const int t1 = 2*i + 1;
        int t2 = 2*i + 2; if (t2 >= NT) t2 -= NT;
        int t3 = 2*i + 3; if (t3 >= NT) t3 -= NT;
        const size_t o1 = (size_t)t1 * 64;
        const size_t o2 = (size_t)t2 * 64;
        const size_t o3 = (size_t)t3 * 64;

        // ===== phase 1: read t0.A.ks0 + t0.B.ks0 (buf0); stage t1.B0; MFMA ks0 m0-3
#pragma unroll
        for (int m = 0; m < 8; ++m) A0[m] = *(const bf16x8*)(As + rowA + m*1024 + g0);
#pragma unroll
        for (int n = 0; n < 4; ++n) Bf0[n] = *(const bf16x8*)(Bs + rowB + n*1024 + g0);
        gload16(bP00 + o1, &Bs[BUF + wofs]);
        gload16(bP01 + o1, &Bs[BUF + 4096 + wofs]);
        SBAR; HWBAR; LGKM0; SBAR;
        __builtin_amdgcn_s_setprio(1);
#pragma unroll
        for (int m = 0; m < 4; ++m)
#pragma unroll
            for (int n = 0; n < 4; ++n)
                acc[m][n] = __builtin_amdgcn_mfma_f32_16x16x32_bf16(A0[m], Bf0[n], acc[m][n], 0, 0, 0);
        __builtin_amdgcn_s_setprio(0);
        SBAR; HWBAR; SBAR;

        // ===== phase 2: read t0.A.ks1; stage t1.B1; MFMA ks0 m4-7; drain lgkm (frees buf0.A)
#pragma unroll
        for (int m = 0; m < 8; ++m) A1[m] = *(const bf16x8*)(As + rowA + m*1024 + g1);
        gload16(bP10 + o1, &Bs[BUF + 8192 + wofs]);
        gload16(bP11 + o1, &Bs[BUF + 12288 + wofs]);
        SBAR; HWBAR; SBAR;
        __builtin_amdgcn_s_setprio(1);
#pragma unroll
        for (int m = 4; m < 8; ++m)
#pragma unroll
            for (int n = 0; n < 4; ++n)
                acc[m][n] = __builtin_amdgcn_mfma_f32_16x16x32_bf16(A0[m], Bf0[n], acc[m][n], 0, 0, 0);
        __builtin_amdgcn_s_setprio(0);
        LGKM0; SBAR; HWBAR; SBAR;

        // ===== phase 3: read t0.B.ks1; stage t2.A0 (buf0); MFMA ks1 m0-3
#pragma unroll
        for (int n = 0; n < 4; ++n) Bf1[n] = *(const bf16x8*)(Bs + rowB + n*1024 + g1);
        gload16(aP00 + o2, &As[wofs]);
        gload16(aP01 + o2, &As[4096 + wofs]);
        SBAR; HWBAR; LGKM0; SBAR;
        __builtin_amdgcn_s_setprio(1);
#pragma unroll
        for (int m = 0; m < 4; ++m)
#pragma unroll
            for (int n = 0; n < 4; ++n)
                acc[m][n] = __builtin_amdgcn_mfma_f32_16x16x32_bf16(A1[m], Bf1[n], acc[m][n], 0, 0, 0);
        __builtin_amdgcn_s_setprio(0);
        SBAR; HWBAR; SBAR;

        // ===== phase 4: stage t2.A1; MFMA ks1 m4-7; vmcnt(4) -> t1 resident
        gload16(aP10 + o2, &As[8192 + wofs]);
        gload16(aP11 + o2, &As[12288 + wofs]);
        SBAR; HWBAR; SBAR;
        __builtin_amdgcn_s_setprio(1);
#pragma unroll
        for (int m = 4; m < 8; ++m)
#pragma unroll
            for (int n = 0; n < 4; ++n)
                acc[m][n] = __builtin_amdgcn_mfma_f32_16x16x32_bf16(A1[m], Bf1[n], acc[m][n], 0, 0, 0);
        __builtin_amdgcn_s_setprio(0);
        VMC4; SBAR; HWBAR; SBAR;

        // ===== phase 5: read t1.A.ks0 + t1.B.ks0 (buf1); stage t2.B0; MFMA ks0 m0-3
#pragma unroll
        for (int m = 0; m < 8; ++m) A0[m] = *(const bf16x8*)(As + BUF + rowA + m*1024 + g0);
#pragma unroll
        for (int n = 0; n < 4; ++n) Bf0[n] = *(const bf16x8*)(Bs + BUF + rowB + n*1024 + g0);
        gload16(bP00 + o2, &Bs[wofs]);
        gload16(bP01 + o2, &Bs[4096 + wofs]);
        SBAR; HWBAR; LGKM0; SBAR;
        __builtin_amdgcn_s_setprio(1);
#pragma unroll
        for (int m = 0; m < 4; ++m)
#pragma unroll
            for (int n = 0; n < 4; ++n)
                acc[m][n] = __builtin_amdgcn_mfma_f32_16x16x32_bf16(A0[m], Bf0[n], acc[m][n], 0, 0, 0);
        __builtin_amdgcn_s_setprio(0);
        SBAR; HWBAR; SBAR;

        // ===== phase 6: read t1.A.ks1; stage t2.B1; MFMA ks0 m4-7; drain lgkm (frees buf1.A)
#pragma unroll
        for (int m = 0; m < 8; ++m) A1[m] = *(const bf16x8*)(As + BUF + rowA + m*1024 + g1);
        gload16(bP10 + o2, &Bs[8192 + wofs]);
        gload16(bP11 + o2, &Bs[12288 + wofs]);
        SBAR; HWBAR; SBAR;
        __builtin_amdgcn_s_setprio(1);
#pragma unroll
        for (int m = 4; m < 8; ++m)
#pragma unroll
            for (int n = 0; n < 4; ++n)
                acc[m][n] = __builtin_amdgcn_mfma_f32_16x16x32_bf16(A0[m], Bf0[n], acc[m][n], 0, 0, 0);
        __builtin_amdgcn_s_setprio(0);
        LGKM0; SBAR; HWBAR; SBAR;

        // ===== phase 7: read t1.B.ks1; stage t3.A0 (buf1); MFMA ks1 m0-3
#pragma unroll
        for (int n = 0; n < 4; ++n) Bf1[n] = *(const bf16x8*)(Bs + BUF + rowB + n*1024 + g1);
        gload16(aP00 + o3, &As[BUF + wofs]);
        gload16(aP01 + o3, &As[BUF + 4096 + wofs]);
        SBAR; HWBAR; LGKM0; SBAR;
        __builtin_amdgcn_s_setprio(1);
#pragma unroll
        for (int m = 0; m < 4; ++m)
#pragma unroll
            for (int n = 0; n < 4; ++n)
                acc[m][n] = __builtin_amdgcn_mfma_f32_16x16x32_bf16(A1[m], Bf1[n], acc[m][n], 0, 0, 0);
        __builtin_amdgcn_s_setprio(0);
        SBAR; HWBAR; SBAR;

        // ===== phase 8: stage t3.A1; MFMA ks1 m4-7; vmcnt(4) -> t2 resident
        gload16(aP10 + o3, &As[BUF + 8192 + wofs]);
        gload16(aP11 + o3, &As[BUF + 12288 + wofs]);
        SBAR; HWBAR; SBAR;
        __builtin_amdgcn_s_setprio(1);
#pragma unroll
        for (int m = 4; m < 8; ++m)
#pragma unroll
            for (int n = 0; n < 4; ++n)
                acc[m][n] = __builtin_amdgcn_mfma_f32_16x16x32_bf16(A1[m], Bf1[n], acc[m][n], 0, 0, 0);
        __builtin_amdgcn_s_setprio(0);
        VMC4; SBAR; HWBAR; SBAR;
    }
}

// ---------------- fp32 -> bf16 conversion ----------------
__global__ void cvt_kernel(const float* __restrict__ in, unsigned short* __restrict__ out, int n4) {
    int i = blockIdx.x * blockDim.x + threadIdx.x;
    int stride = gridDim.x * blockDim.x;
    for (; i < n4; i += stride) {
        float4 v = reinterpret_cast<const float4*>(in)[i];
        ushort4 o;
        o.x = f2bf(v.x); o.y = f2bf(v.y); o.z = f2bf(v.z); o.w = f2bf(v.w);
        reinterpret_cast<ushort4*>(out)[i] = o;
    }
}

// ---------------- router ----------------
__global__ __launch_bounds__(64) void router_kernel(
    const float* __restrict__ x, const float* __restrict__ rw, const float* __restrict__ rb,
    int* __restrict__ tidx, float* __restrict__ tgate, int* __restrict__ counts)
{
    int t = blockIdx.x;
    int lane = threadIdx.x;
    const float* xr = x + (size_t)t * DIM;
    float acc[NEXP];
#pragma unroll
    for (int e = 0; e < NEXP; ++e) acc[e] = 0.f;
    for (int i = lane; i < DIM; i += 64) {
        float xv = xr[i];
#pragma unroll
        for (int e = 0; e < NEXP; ++e) acc[e] += xv * rw[e*DIM + i];
    }
#pragma unroll
    for (int e = 0; e < NEXP; ++e) {
        float v = acc[e];
#pragma unroll
        for (int off = 32; off >= 1; off >>= 1) v += __shfl_xor(v, off);
        acc[e] = v + rb[e];
    }
    int i0 = 0;
#pragma unroll
    for (int e = 1; e < NEXP; ++e) if (acc[e] > acc[i0]) i0 = e;
    int i1 = (i0 == 0) ? 1 : 0;
#pragma unroll
    for (int e = 0; e < NEXP; ++e) if (e != i0 && acc[e] > acc[i1]) i1 = e;

    float mx = acc[i0];
    float den = 0.f;
    float pe[NEXP];
#pragma unroll
    for (int e = 0; e < NEXP; ++e) { pe[e] = __expf(acc[e] - mx); den += pe[e]; }
    float inv = 1.f / den;
    if (lane == 0) {
        tidx[2*t]   = i0;  tidx[2*t+1]  = i1;
        tgate[2*t]  = pe[i0]*inv; tgate[2*t+1] = pe[i1]*inv;
        atomicAdd(&counts[i0], 1);
        atomicAdd(&counts[i1], 1);
    }
}

__global__ void prefix_kernel(const int* __restrict__ counts, int* __restrict__ offsets) {
    if (threadIdx.x == 0 && blockIdx.x == 0) {
        int s = 0;
        for (int e = 0; e < NEXP; ++e) { offsets[e] = s; s += counts[e]; }
    }
}

__global__ void assign_kernel(const int* __restrict__ tidx, const float* __restrict__ tgate,
                              const int* __restrict__ offsets, int* __restrict__ counts2,
                              int* __restrict__ rowtok, float* __restrict__ rowgate)
{
    int t = blockIdx.x * blockDim.x + threadIdx.x;
    if (t >= N_TOK) return;
#pragma unroll
    for (int k = 0; k < TOPK; ++k) {
        int e = tidx[2*t+k];
        int pos = atomicAdd(&counts2[e], 1);
        int r = offsets[e] + pos;
        rowtok[r]  = t;
        rowgate[r] = tgate[2*t+k];
    }
}

// ---------------- GEMM1: hg = gelu(Xg @ w1[e]^T + b1[e]) ----------------
__global__ __launch_bounds__(512, 2) void gemm1_kernel(
    const unsigned short* __restrict__ xb,
    const unsigned short* __restrict__ w1b,
    const float* __restrict__ b1,
    const int* __restrict__ rowtok,
    const int* __restrict__ counts, const int* __restrict__ offsets,
    unsigned short* __restrict__ hg)
{
    __shared__ unsigned short As[32768];
    __shared__ unsigned short Bs[32768];
    __shared__ int rowids[256];

    int e   = blockIdx.z;
    int cnt = counts[e];
    int mt  = blockIdx.y;
    if (mt * 256 >= cnt) return;
    int base  = offsets[e];
    int nbase = blockIdx.x * 256;

    int tid = threadIdx.x;
    if (tid < 256) {
        int r = mt*256 + tid;
        rowids[tid] = rowtok[base + (r < cnt ? r : cnt - 1)];
    }
    __syncthreads();

    int l = tid & 63, w = tid >> 6;
    int wofs = w * 512;                       // wave's LDS chunk within a 64-row load
    int srow = (w << 3) | (l >> 3);           // 0..63 row within a 64-row load
    int sgel = ((l & 7) ^ (l >> 3)) << 3;     // pre-swizzled source granule (elements)

    const unsigned short* wE = w1b + (size_t)e * HID * DIM;
    const unsigned short* aP00 = xb + (size_t)rowids[      srow] * DIM + sgel;
    const unsigned short* aP01 = xb + (size_t)rowids[ 64 + srow] * DIM + sgel;
    const unsigned short* aP10 = xb + (size_t)rowids[128 + srow] * DIM + sgel;
    const unsigned short* aP11 = xb + (size_t)rowids[192 + srow] * DIM + sgel;
    const unsigned short* bP00 = wE + (size_t)(nbase +       srow) * DIM + sgel;
    const unsigned short* bP01 = wE + (size_t)(nbase +  64 + srow) * DIM + sgel;
    const unsigned short* bP10 = wE + (size_t)(nbase + 128 + srow) * DIM + sgel;
    const unsigned short* bP11 = wE + (size_t)(nbase + 192 + srow) * DIM + sgel;

    int fr = l & 15, hi = l >> 4, lo = l & 7;
    int wm = w >> 2, wn = w & 3;
    int rowA = (wm*128 + fr) * 64;
    int rowB = (wn*64  + fr) * 64;
    int g0 = (hi ^ lo) << 3;                  // ks0 swizzled read granule
    int g1 = ((4 | hi) ^ lo) << 3;            // ks1

    f32x4 acc[8][4];
#pragma unroll
    for (int m = 0; m < 8; ++m)
#pragma unroll
        for (int n = 0; n < 4; ++n)
#pragma unroll
            for (int j = 0; j < 4; ++j) acc[m][n][j] = 0.f;

    kloop8<DIM/64>(As, Bs, aP00, aP01, aP10, aP11, bP00, bP01, bP10, bP11,
                   wofs, rowA, rowB, g0, g1, acc);

    const float* b1e = b1 + (size_t)e * HID;
#pragma unroll
    for (int m = 0; m < 8; ++m) {
        int rb_ = mt*256 + wm*128 + m*16 + hi*4;
#pragma unroll
        for (int j = 0; j < 4; ++j) {
            int grow = rb_ + j;
            if (grow < cnt) {
                size_t rowoff = (size_t)(base + grow) * HID;
#pragma unroll
                for (int n = 0; n < 4; ++n) {
                    int col = nbase + wn*64 + n*16 + fr;
                    float v = acc[m][n][j] + b1e[col];
                    float u  = 0.7978845608028654f * (v + 0.044715f * v * v * v);
                    float ex = __expf(2.f * u);
                    float th = 1.f - 2.f / (ex + 1.f);
                    hg[rowoff + col] = f2bf(0.5f * v * (1.f + th));
                }
            }
        }
    }
}

// ---------------- GEMM2: y[tok] += gate * (hg @ w2[e]^T + b2[e]) ----------------
__global__ __launch_bounds__(512, 2) void gemm2_kernel(
    const unsigned short* __restrict__ hg,
    const unsigned short* __restrict__ w2b,
    const float* __restrict__ b2,
    const int* __restrict__ rowtok, const float* __restrict__ rowgate,
    const int* __restrict__ counts, const int* __restrict__ offsets,
    float* __restrict__ y)
{
    __shared__ unsigned short As[32768];
    __shared__ unsigned short Bs[32768];

    int e   = blockIdx.z;
    int cnt = counts[e];
    int mt  = blockIdx.y;
    if (mt * 256 >= cnt) return;
    int base  = offsets[e];
    int nbase = blockIdx.x * 256;

    int tid = threadIdx.x;
    int l = tid & 63, w = tid >> 6;
    int wofs = w * 512;
    int srow = (w << 3) | (l >> 3);
    int sgel = ((l & 7) ^ (l >> 3)) << 3;

    int r00 = mt*256 +       srow; if (r00 >= cnt) r00 = cnt - 1;
    int r01 = mt*256 +  64 + srow; if (r01 >= cnt) r01 = cnt - 1;
    int r10 = mt*256 + 128 + srow; if (r10 >= cnt) r10 = cnt - 1;
    int r11 = mt*256 + 192 + srow; if (r11 >= cnt) r11 = cnt - 1;

    const unsigned short* wE = w2b + (size_t)e * DIM * HID;
    const unsigned short* aP00 = hg + (size_t)(base + r00) * HID + sgel;
    const unsigned short* aP01 = hg + (size_t)(base + r01) * HID + sgel;
    const unsigned short* aP10 = hg + (size_t)(base + r10) * HID + sgel;
    const unsigned short* aP11 = hg + (size_t)(base + r11) * HID + sgel;
    const unsigned short* bP00 = wE + (size_t)(nbase +       srow) * HID + sgel;
    const unsigned short* bP01 = wE + (size_t)(nbase +  64 + srow) * HID + sgel;
    const unsigned short* bP10 = wE + (size_t)(nbase + 128 + srow) * HID + sgel;
    const unsigned short* bP11 = wE + (size_t)(nbase + 192 + srow) * HID + sgel;

    int fr = l & 15, hi = l >> 4, lo = l & 7;
    int wm = w >> 2, wn = w & 3;
    int rowA = (wm*128 + fr) * 64;
    int rowB = (wn*64  + fr) * 64;
    int g0 = (hi ^ lo) << 3;
    int g1 = ((4 | hi) ^ lo) << 3;

    f32x4 acc[8][4];
#pragma unroll
    for (int m = 0; m < 8; ++m)
#pragma unroll
        for (int n = 0; n < 4; ++n)
#pragma unroll
            for (int j = 0; j < 4; ++j) acc[m][n][j] = 0.f;

    kloop8<HID/64>(As, Bs, aP00, aP01, aP10, aP11, bP00, bP01, bP10, bP11,
                   wofs, rowA, rowB, g0, g1, acc);

    const float* b2e = b2 + (size_t)e * DIM;
#pragma unroll
    for (int m = 0; m < 8; ++m) {
        int rb_ = mt*256 + wm*128 + m*16 + hi*4;
#pragma unroll
        for (int j = 0; j < 4; ++j) {
            int grow = rb_ + j;
            if (grow < cnt) {
                int tok = rowtok[base + grow];
                float g = rowgate[base + grow];
#pragma unroll
                for (int n = 0; n < 4; ++n) {
                    int col = nbase + wn*64 + n*16 + fr;
                    float v = acc[m][n][j] + b2e[col];
                    atomicAdd(&y[(size_t)tok * DIM + col], g * v);
                }
            }
        }
    }
}

// ---------------- workspace layout ----------------
static constexpr size_t XB_OFF   = 0;
static constexpr size_t W1B_OFF  = XB_OFF  + (size_t)N_TOK * DIM * 2;
static constexpr size_t W2B_OFF  = W1B_OFF + (size_t)NEXP * HID * DIM * 2;
static constexpr size_t HG_OFF   = W2B_OFF + (size_t)NEXP * DIM * HID * 2;
static constexpr size_t RT_OFF   = HG_OFF  + (size_t)M_TOT * HID * 2;
static constexpr size_t RG_OFF   = RT_OFF  + (size_t)M_TOT * 4;
static constexpr size_t TI_OFF   = RG_OFF  + (size_t)M_TOT * 4;
static constexpr size_t TG_OFF   = TI_OFF  + (size_t)N_TOK * TOPK * 4;
static constexpr size_t META_OFF = TG_OFF  + (size_t)N_TOK * TOPK * 4;
static constexpr size_t WS_NEED  = META_OFF + 256;

extern "C" void kernel_launch(void* const* d_in, const int* in_sizes, int n_in,
                              void* d_out, int out_size, void* d_ws, size_t ws_size,
                              hipStream_t stream)
{
    if (ws_size < WS_NEED) return;

    const float* x  = (const float*)d_in[0];
    const float* rw = (const float*)d_in[1];
    const float* rb = (const float*)d_in[2];
    const float* w1 = (const float*)d_in[3];
    const float* b1 = (const float*)d_in[4];
    const float* w2 = (const float*)d_in[5];
    const float* b2 = (const float*)d_in[6];
    float* y = (float*)d_out;

    char* ws = (char*)d_ws;
    unsigned short* xb  = (unsigned short*)(ws + XB_OFF);
    unsigned short* w1b = (unsigned short*)(ws + W1B_OFF);
    unsigned short* w2b = (unsigned short*)(ws + W2B_OFF);
    unsigned short* hg  = (unsigned short*)(ws + HG_OFF);
    int*   rowtok  = (int*)  (ws + RT_OFF);
    float* rowgate = (float*)(ws + RG_OFF);
    int*   tidx    = (int*)  (ws + TI_OFF);
    float* tgate   = (float*)(ws + TG_OFF);
    int*   meta    = (int*)  (ws + META_OFF);
    int* counts  = meta;
    int* counts2 = meta + 8;
    int* offsets = meta + 16;

    hipMemsetAsync(meta, 0, 64, stream);
    hipMemsetAsync(y, 0, (size_t)out_size * 4, stream);

    cvt_kernel<<<2048, 256, 0, stream>>>(x,  xb,  N_TOK*DIM/4);
    cvt_kernel<<<2048, 256, 0, stream>>>(w1, w1b, NEXP*HID*DIM/4);
    cvt_kernel<<<2048, 256, 0, stream>>>(w2, w2b, NEXP*DIM*HID/4);

    router_kernel<<<N_TOK, 64, 0, stream>>>(x, rw, rb, tidx, tgate, counts);
    prefix_kernel<<<1, 64, 0, stream>>>(counts, offsets);
    assign_kernel<<<N_TOK/256, 256, 0, stream>>>(tidx, tgate, offsets, counts2, rowtok, rowgate);

    gemm1_kernel<<<dim3(HID/256, 32, NEXP), 512, 0, stream>>>(xb, w1b, b1, rowtok, counts, offsets, hg);
    gemm2_kernel<<<dim3(DIM/256, 32, NEXP), 512, 0, stream>>>(hg, w2b, b2, rowtok, rowgate, counts, offsets, y);
}

// Round 4
// 994.738 us; speedup vs baseline: 1.0077x; 1.0077x over previous
//
#include <hip/hip_runtime.h>
#include <hip/hip_bf16.h>

#define N_TOK 8192
#define DIM   1024
#define HID   4096
#define NEXP  8
#define TOPK  2
#define M_TOT (N_TOK*TOPK)

typedef __bf16 bf16x8 __attribute__((ext_vector_type(8)));
typedef float  f32x4  __attribute__((ext_vector_type(4)));

__device__ __forceinline__ unsigned short f2bf(float f) {
    union { __hip_bfloat16 h; unsigned short u; } c;
    c.h = __float2bfloat16(f);
    return c.u;
}

__device__ __forceinline__ void gload16(const unsigned short* g, unsigned short* l) {
    __builtin_amdgcn_global_load_lds(
        (const __attribute__((address_space(1))) void*)g,
        (__attribute__((address_space(3))) void*)l,
        16, 0, 0);
}

#define HWBAR asm volatile("s_barrier" ::: "memory")
#define LGKM0 asm volatile("s_waitcnt lgkmcnt(0)" ::: "memory")
#define VMC4  asm volatile("s_waitcnt vmcnt(4)" ::: "memory")

// ---------------------------------------------------------------------------
// 8-phase K-loop, 256x256 tile, BK=64, 8 waves (2M x 4N), dbuf LDS.
// Granule swizzle: LDS[row][slot] holds source granule slot^(row&7).
// Stage/iter: ph1,2: t1.B  ph3,4: t2.A  ph5,6: t2.B  ph7,8: t3.A.
// vmcnt(4) at ph4/ph8 only; WAR lgkmcnt(0) at ph2/ph6 (A-region overwrite).
// Compiler left free to schedule within phases (no sched_barrier pinning).
// ---------------------------------------------------------------------------
template<int NT>
__device__ __forceinline__ void kloop8(
    unsigned short* As, unsigned short* Bs,
    const unsigned short* aP00, const unsigned short* aP01,
    const unsigned short* aP10, const unsigned short* aP11,
    const unsigned short* bP00, const unsigned short* bP01,
    const unsigned short* bP10, const unsigned short* bP11,
    int wofs, int rowA, int rowB, int g0, int g1,
    f32x4 (&acc)[8][4])
{
    constexpr int BUF = 16384;
    bf16x8 A0[8], A1[8], Bf0[4], Bf1[4];

    // prologue: stage t0 (A+B) and t1.A
    gload16(aP00, &As[wofs]);
    gload16(aP01, &As[4096 + wofs]);
    gload16(aP10, &As[8192 + wofs]);
    gload16(aP11, &As[12288 + wofs]);
    gload16(bP00, &Bs[wofs]);
    gload16(bP01, &Bs[4096 + wofs]);
    gload16(bP10, &Bs[8192 + wofs]);
    gload16(bP11, &Bs[12288 + wofs]);
    gload16(aP00 + 64, &As[BUF + wofs]);
    gload16(aP01 + 64, &As[BUF + 4096 + wofs]);
    gload16(aP10 + 64, &As[BUF + 8192 + wofs]);
    gload16(aP11 + 64, &As[BUF + 12288 + wofs]);
    VMC4; HWBAR;

    for (int i = 0; i < NT/2; ++i) {
        const int t1 = 2*i + 1;
        int t2 = 2*i + 2; if (t2 >= NT) t2 -= NT;
        int t3 = 2*i + 3; if (t3 >= NT) t3 -= NT;
        const size_t o1 = (size_t)t1 * 64;
        const size_t o2 = (size_t)t2 * 64;
        const size_t o3 = (size_t)t3 * 64;

        // ph1: read t0.{A,B}.ks0; stage t1.B0; MFMA ks0 m0-3
#pragma unroll
        for (int m = 0; m < 8; ++m) A0[m] = *(const bf16x8*)(As + rowA + m*1024 + g0);
#pragma unroll
        for (int n = 0; n < 4; ++n) Bf0[n] = *(const bf16x8*)(Bs + rowB + n*1024 + g0);
        gload16(bP00 + o1, &Bs[BUF + wofs]);
        gload16(bP01 + o1, &Bs[BUF + 4096 + wofs]);
        HWBAR;
        __builtin_amdgcn_s_setprio(1);
#pragma unroll
        for (int m = 0; m < 4; ++m)
#pragma unroll
            for (int n = 0; n < 4; ++n)
                acc[m][n] = __builtin_amdgcn_mfma_f32_16x16x32_bf16(A0[m], Bf0[n], acc[m][n], 0, 0, 0);
        __builtin_amdgcn_s_setprio(0);
        HWBAR;

        // ph2: read t0.A.ks1; stage t1.B1; MFMA ks0 m4-7; WAR drain
#pragma unroll
        for (int m = 0; m < 8; ++m) A1[m] = *(const bf16x8*)(As + rowA + m*1024 + g1);
        gload16(bP10 + o1, &Bs[BUF + 8192 + wofs]);
        gload16(bP11 + o1, &Bs[BUF + 12288 + wofs]);
        HWBAR;
        __builtin_amdgcn_s_setprio(1);
#pragma unroll
        for (int m = 4; m < 8; ++m)
#pragma unroll
            for (int n = 0; n < 4; ++n)
                acc[m][n] = __builtin_amdgcn_mfma_f32_16x16x32_bf16(A0[m], Bf0[n], acc[m][n], 0, 0, 0);
        __builtin_amdgcn_s_setprio(0);
        LGKM0; HWBAR;

        // ph3: read t0.B.ks1; stage t2.A0; MFMA ks1 m0-3
#pragma unroll
        for (int n = 0; n < 4; ++n) Bf1[n] = *(const bf16x8*)(Bs + rowB + n*1024 + g1);
        gload16(aP00 + o2, &As[wofs]);
        gload16(aP01 + o2, &As[4096 + wofs]);
        HWBAR;
        __builtin_amdgcn_s_setprio(1);
#pragma unroll
        for (int m = 0; m < 4; ++m)
#pragma unroll
            for (int n = 0; n < 4; ++n)
                acc[m][n] = __builtin_amdgcn_mfma_f32_16x16x32_bf16(A1[m], Bf1[n], acc[m][n], 0, 0, 0);
        __builtin_amdgcn_s_setprio(0);
        HWBAR;

        // ph4: stage t2.A1; MFMA ks1 m4-7; vmcnt(4) -> t1 resident
        gload16(aP10 + o2, &As[8192 + wofs]);
        gload16(aP11 + o2, &As[12288 + wofs]);
        HWBAR;
        __builtin_amdgcn_s_setprio(1);
#pragma unroll
        for (int m = 4; m < 8; ++m)
#pragma unroll
            for (int n = 0; n < 4; ++n)
                acc[m][n] = __builtin_amdgcn_mfma_f32_16x16x32_bf16(A1[m], Bf1[n], acc[m][n], 0, 0, 0);
        __builtin_amdgcn_s_setprio(0);
        VMC4; HWBAR;

        // ph5: read t1.{A,B}.ks0 (buf1); stage t2.B0; MFMA ks0 m0-3
#pragma unroll
        for (int m = 0; m < 8; ++m) A0[m] = *(const bf16x8*)(As + BUF + rowA + m*1024 + g0);
#pragma unroll
        for (int n = 0; n < 4; ++n) Bf0[n] = *(const bf16x8*)(Bs + BUF + rowB + n*1024 + g0);
        gload16(bP00 + o2, &Bs[wofs]);
        gload16(bP01 + o2, &Bs[4096 + wofs]);
        HWBAR;
        __builtin_amdgcn_s_setprio(1);
#pragma unroll
        for (int m = 0; m < 4; ++m)
#pragma unroll
            for (int n = 0; n < 4; ++n)
                acc[m][n] = __builtin_amdgcn_mfma_f32_16x16x32_bf16(A0[m], Bf0[n], acc[m][n], 0, 0, 0);
        __builtin_amdgcn_s_setprio(0);
        HWBAR;

        // ph6: read t1.A.ks1; stage t2.B1; MFMA ks0 m4-7; WAR drain
#pragma unroll
        for (int m = 0; m < 8; ++m) A1[m] = *(const bf16x8*)(As + BUF + rowA + m*1024 + g1);
        gload16(bP10 + o2, &Bs[8192 + wofs]);
        gload16(bP11 + o2, &Bs[12288 + wofs]);
        HWBAR;
        __builtin_amdgcn_s_setprio(1);
#pragma unroll
        for (int m = 4; m < 8; ++m)
#pragma unroll
            for (int n = 0; n < 4; ++n)
                acc[m][n] = __builtin_amdgcn_mfma_f32_16x16x32_bf16(A0[m], Bf0[n], acc[m][n], 0, 0, 0);
        __builtin_amdgcn_s_setprio(0);
        LGKM0; HWBAR;

        // ph7: read t1.B.ks1; stage t3.A0; MFMA ks1 m0-3
#pragma unroll
        for (int n = 0; n < 4; ++n) Bf1[n] = *(const bf16x8*)(Bs + BUF + rowB + n*1024 + g1);
        gload16(aP00 + o3, &As[BUF + wofs]);
        gload16(aP01 + o3, &As[BUF + 4096 + wofs]);
        HWBAR;
        __builtin_amdgcn_s_setprio(1);
#pragma unroll
        for (int m = 0; m < 4; ++m)
#pragma unroll
            for (int n = 0; n < 4; ++n)
                acc[m][n] = __builtin_amdgcn_mfma_f32_16x16x32_bf16(A1[m], Bf1[n], acc[m][n], 0, 0, 0);
        __builtin_amdgcn_s_setprio(0);
        HWBAR;

        // ph8: stage t3.A1; MFMA ks1 m4-7; vmcnt(4) -> t2 resident
        gload16(aP10 + o3, &As[BUF + 8192 + wofs]);
        gload16(aP11 + o3, &As[BUF + 12288 + wofs]);
        HWBAR;
        __builtin_amdgcn_s_setprio(1);
#pragma unroll
        for (int m = 4; m < 8; ++m)
#pragma unroll
            for (int n = 0; n < 4; ++n)
                acc[m][n] = __builtin_amdgcn_mfma_f32_16x16x32_bf16(A1[m], Bf1[n], acc[m][n], 0, 0, 0);
        __builtin_amdgcn_s_setprio(0);
        VMC4; HWBAR;
    }
}

// ---------------- fp32 -> bf16 conversion ----------------
__global__ void cvt_kernel(const float* __restrict__ in, unsigned short* __restrict__ out, int n4) {
    int i = blockIdx.x * blockDim.x + threadIdx.x;
    int stride = gridDim.x * blockDim.x;
    for (; i < n4; i += stride) {
        float4 v = reinterpret_cast<const float4*>(in)[i];
        ushort4 o;
        o.x = f2bf(v.x); o.y = f2bf(v.y); o.z = f2bf(v.z); o.w = f2bf(v.w);
        reinterpret_cast<ushort4*>(out)[i] = o;
    }
}

// ---------------- router (also emits xb bf16) ----------------
__global__ __launch_bounds__(64) void router_kernel(
    const float* __restrict__ x, const float* __restrict__ rw, const float* __restrict__ rb,
    unsigned short* __restrict__ xb,
    int* __restrict__ tidx, float* __restrict__ tgate, int* __restrict__ counts)
{
    int t = blockIdx.x;
    int lane = threadIdx.x;
    const float4* xr4 = reinterpret_cast<const float4*>(x + (size_t)t * DIM);
    ushort4* xb4 = reinterpret_cast<ushort4*>(xb + (size_t)t * DIM);
    float acc[NEXP];
#pragma unroll
    for (int e = 0; e < NEXP; ++e) acc[e] = 0.f;
#pragma unroll
    for (int i = 0; i < 4; ++i) {
        float4 xv = xr4[lane + 64*i];
        ushort4 o;
        o.x = f2bf(xv.x); o.y = f2bf(xv.y); o.z = f2bf(xv.z); o.w = f2bf(xv.w);
        xb4[lane + 64*i] = o;
#pragma unroll
        for (int e = 0; e < NEXP; ++e) {
            float4 wv = reinterpret_cast<const float4*>(rw + e*DIM)[lane + 64*i];
            acc[e] += xv.x*wv.x + xv.y*wv.y + xv.z*wv.z + xv.w*wv.w;
        }
    }
#pragma unroll
    for (int e = 0; e < NEXP; ++e) {
        float v = acc[e];
#pragma unroll
        for (int off = 32; off >= 1; off >>= 1) v += __shfl_xor(v, off);
        acc[e] = v + rb[e];
    }
    int i0 = 0;
#pragma unroll
    for (int e = 1; e < NEXP; ++e) if (acc[e] > acc[i0]) i0 = e;
    int i1 = (i0 == 0) ? 1 : 0;
#pragma unroll
    for (int e = 0; e < NEXP; ++e) if (e != i0 && acc[e] > acc[i1]) i1 = e;

    float mx = acc[i0];
    float den = 0.f;
    float pe[NEXP];
#pragma unroll
    for (int e = 0; e < NEXP; ++e) { pe[e] = __expf(acc[e] - mx); den += pe[e]; }
    float inv = 1.f / den;
    if (lane == 0) {
        tidx[2*t]   = i0;  tidx[2*t+1]  = i1;
        tgate[2*t]  = pe[i0]*inv; tgate[2*t+1] = pe[i1]*inv;
        atomicAdd(&counts[i0], 1);
        atomicAdd(&counts[i1], 1);
    }
}

// ---------------- plan: offsets + worklists ----------------
__global__ void plan_kernel(const int* __restrict__ counts, int* __restrict__ offsets,
                            int* __restrict__ wl1, int* __restrict__ wl2, int* __restrict__ nits)
{
    if (threadIdx.x == 0 && blockIdx.x == 0) {
        int s = 0;
        for (int e = 0; e < NEXP; ++e) { offsets[e] = s; s += counts[e]; }
        int k1 = 0;
        for (int e = 0; e < NEXP; ++e) {
            int T = (counts[e] + 255) >> 8;
            for (int nt = 0; nt < HID/256; ++nt)
                for (int mt = 0; mt < T; ++mt)
                    wl1[k1++] = (e << 20) | (mt << 8) | nt;
        }
        int k2 = 0;
        for (int e = 0; e < NEXP; ++e) {
            int T = (counts[e] + 255) >> 8;
            for (int nt = 0; nt < DIM/256; ++nt)
                for (int mt = 0; mt < T; ++mt)
                    wl2[k2++] = (e << 20) | (mt << 8) | nt;
        }
        nits[0] = k1; nits[1] = k2;
    }
}

__global__ void assign_kernel(const int* __restrict__ tidx, const float* __restrict__ tgate,
                              const int* __restrict__ offsets, int* __restrict__ counts2,
                              int* __restrict__ rowtok, float* __restrict__ rowgate)
{
    int t = blockIdx.x * blockDim.x + threadIdx.x;
    if (t >= N_TOK) return;
#pragma unroll
    for (int k = 0; k < TOPK; ++k) {
        int e = tidx[2*t+k];
        int pos = atomicAdd(&counts2[e], 1);
        int r = offsets[e] + pos;
        rowtok[r]  = t;
        rowgate[r] = tgate[2*t+k];
    }
}

// ---------------- GEMM1: hg = gelu(Xg @ w1[e]^T + b1[e]) ----------------
__global__ __launch_bounds__(512, 2) void gemm1_kernel(
    const unsigned short* __restrict__ xb,
    const unsigned short* __restrict__ w1b,
    const float* __restrict__ b1,
    const int* __restrict__ rowtok,
    const int* __restrict__ counts, const int* __restrict__ offsets,
    const int* __restrict__ wl, const int* __restrict__ nits, int* __restrict__ steal,
    unsigned short* __restrict__ hg)
{
    __shared__ unsigned short As[32768];
    __shared__ unsigned short Bs[32768];
    __shared__ int rowids[256];
    __shared__ int curs;

    int tid = threadIdx.x;
    int l = tid & 63, w = tid >> 6;
    int wofs = w * 512;
    int srow = (w << 3) | (l >> 3);
    int sgel = ((l & 7) ^ (l >> 3)) << 3;
    int fr = l & 15, hi = l >> 4, lo = l & 7;
    int wm = w >> 2, wn = w & 3;
    int rowA = (wm*128 + fr) * 64;
    int rowB = (wn*64  + fr) * 64;
    int g0 = (hi ^ lo) << 3;
    int g1 = ((4 | hi) ^ lo) << 3;
    const int nitems = nits[0];

    while (true) {
        if (tid == 0) curs = atomicAdd(steal, 1);
        __syncthreads();
        int it = curs;
        if (it >= nitems) break;
        int wle = wl[it];
        int e = wle >> 20, mt = (wle >> 8) & 0xFFF, nt = wle & 0xFF;
        int cnt = counts[e];
        int base = offsets[e];
        int nbase = nt * 256;

        if (tid < 256) {
            int r = mt*256 + tid;
            rowids[tid] = rowtok[base + (r < cnt ? r : cnt - 1)];
        }
        __syncthreads();

        const unsigned short* wE = w1b + (size_t)e * HID * DIM;
        const unsigned short* aP00 = xb + (size_t)rowids[      srow] * DIM + sgel;
        const unsigned short* aP01 = xb + (size_t)rowids[ 64 + srow] * DIM + sgel;
        const unsigned short* aP10 = xb + (size_t)rowids[128 + srow] * DIM + sgel;
        const unsigned short* aP11 = xb + (size_t)rowids[192 + srow] * DIM + sgel;
        const unsigned short* bP00 = wE + (size_t)(nbase +       srow) * DIM + sgel;
        const unsigned short* bP01 = wE + (size_t)(nbase +  64 + srow) * DIM + sgel;
        const unsigned short* bP10 = wE + (size_t)(nbase + 128 + srow) * DIM + sgel;
        const unsigned short* bP11 = wE + (size_t)(nbase + 192 + srow) * DIM + sgel;

        f32x4 acc[8][4];
#pragma unroll
        for (int m = 0; m < 8; ++m)
#pragma unroll
            for (int n = 0; n < 4; ++n)
#pragma unroll
                for (int j = 0; j < 4; ++j) acc[m][n][j] = 0.f;

        kloop8<DIM/64>(As, Bs, aP00, aP01, aP10, aP11, bP00, bP01, bP10, bP11,
                       wofs, rowA, rowB, g0, g1, acc);

        const float* b1e = b1 + (size_t)e * HID;
#pragma unroll
        for (int m = 0; m < 8; ++m) {
            int rb_ = mt*256 + wm*128 + m*16 + hi*4;
#pragma unroll
            for (int j = 0; j < 4; ++j) {
                int grow = rb_ + j;
                if (grow < cnt) {
                    size_t rowoff = (size_t)(base + grow) * HID;
#pragma unroll
                    for (int n = 0; n < 4; ++n) {
                        int col = nbase + wn*64 + n*16 + fr;
                        float v = acc[m][n][j] + b1e[col];
                        float u  = 0.7978845608028654f * (v + 0.044715f * v * v * v);
                        float ex = __expf(2.f * u);
                        float th = 1.f - 2.f / (ex + 1.f);
                        hg[rowoff + col] = f2bf(0.5f * v * (1.f + th));
                    }
                }
            }
        }
        __syncthreads();   // full vmcnt/lgkm drain + barrier: isolates items
    }
}

// ---------------- GEMM2: y[tok] += gate * (hg @ w2[e]^T + b2[e]) ----------------
__global__ __launch_bounds__(512, 2) void gemm2_kernel(
    const unsigned short* __restrict__ hg,
    const unsigned short* __restrict__ w2b,
    const float* __restrict__ b2,
    const int* __restrict__ rowtok, const float* __restrict__ rowgate,
    const int* __restrict__ counts, const int* __restrict__ offsets,
    const int* __restrict__ wl, const int* __restrict__ nits, int* __restrict__ steal,
    float* __restrict__ y)
{
    __shared__ unsigned short As[32768];
    __shared__ unsigned short Bs[32768];
    __shared__ int curs;

    int tid = threadIdx.x;
    int l = tid & 63, w = tid >> 6;
    int wofs = w * 512;
    int srow = (w << 3) | (l >> 3);
    int sgel = ((l & 7) ^ (l >> 3)) << 3;
    int fr = l & 15, hi = l >> 4, lo = l & 7;
    int wm = w >> 2, wn = w & 3;
    int rowA = (wm*128 + fr) * 64;
    int rowB = (wn*64  + fr) * 64;
    int g0 = (hi ^ lo) << 3;
    int g1 = ((4 | hi) ^ lo) << 3;
    const int nitems = nits[1];

    while (true) {
        if (tid == 0) curs = atomicAdd(steal, 1);
        __syncthreads();
        int it = curs;
        if (it >= nitems) break;
        int wle = wl[it];
        int e = wle >> 20, mt = (wle >> 8) & 0xFFF, nt = wle & 0xFF;
        int cnt = counts[e];
        int base = offsets[e];
        int nbase = nt * 256;

        int r00 = mt*256 +       srow; if (r00 >= cnt) r00 = cnt - 1;
        int r01 = mt*256 +  64 + srow; if (r01 >= cnt) r01 = cnt - 1;
        int r10 = mt*256 + 128 + srow; if (r10 >= cnt) r10 = cnt - 1;
        int r11 = mt*256 + 192 + srow; if (r11 >= cnt) r11 = cnt - 1;

        const unsigned short* wE = w2b + (size_t)e * DIM * HID;
        const unsigned short* aP00 = hg + (size_t)(base + r00) * HID + sgel;
        const unsigned short* aP01 = hg + (size_t)(base + r01) * HID + sgel;
        const unsigned short* aP10 = hg + (size_t)(base + r10) * HID + sgel;
        const unsigned short* aP11 = hg + (size_t)(base + r11) * HID + sgel;
        const unsigned short* bP00 = wE + (size_t)(nbase +       srow) * HID + sgel;
        const unsigned short* bP01 = wE + (size_t)(nbase +  64 + srow) * HID + sgel;
        const unsigned short* bP10 = wE + (size_t)(nbase + 128 + srow) * HID + sgel;
        const unsigned short* bP11 = wE + (size_t)(nbase + 192 + srow) * HID + sgel;

        f32x4 acc[8][4];
#pragma unroll
        for (int m = 0; m < 8; ++m)
#pragma unroll
            for (int n = 0; n < 4; ++n)
#pragma unroll
                for (int j = 0; j < 4; ++j) acc[m][n][j] = 0.f;

        kloop8<HID/64>(As, Bs, aP00, aP01, aP10, aP11, bP00, bP01, bP10, bP11,
                       wofs, rowA, rowB, g0, g1, acc);

        const float* b2e = b2 + (size_t)e * DIM;
#pragma unroll
        for (int m = 0; m < 8; ++m) {
            int rb_ = mt*256 + wm*128 + m*16 + hi*4;
#pragma unroll
            for (int j = 0; j < 4; ++j) {
                int grow = rb_ + j;
                if (grow < cnt) {
                    int tok = rowtok[base + grow];
                    float g = rowgate[base + grow];
#pragma unroll
                    for (int n = 0; n < 4; ++n) {
                        int col = nbase + wn*64 + n*16 + fr;
                        float v = acc[m][n][j] + b2e[col];
                        atomicAdd(&y[(size_t)tok * DIM + col], g * v);
                    }
                }
            }
        }
        __syncthreads();
    }
}

// ---------------- workspace layout ----------------
static constexpr size_t XB_OFF   = 0;
static constexpr size_t W1B_OFF  = XB_OFF  + (size_t)N_TOK * DIM * 2;
static constexpr size_t W2B_OFF  = W1B_OFF + (size_t)NEXP * HID * DIM * 2;
static constexpr size_t HG_OFF   = W2B_OFF + (size_t)NEXP * DIM * HID * 2;
static constexpr size_t RT_OFF   = HG_OFF  + (size_t)M_TOT * HID * 2;
static constexpr size_t RG_OFF   = RT_OFF  + (size_t)M_TOT * 4;
static constexpr size_t TI_OFF   = RG_OFF  + (size_t)M_TOT * 4;
static constexpr size_t TG_OFF   = TI_OFF  + (size_t)N_TOK * TOPK * 4;
static constexpr size_t META_OFF = TG_OFF  + (size_t)N_TOK * TOPK * 4;
static constexpr size_t WL1_OFF  = META_OFF + 256;
static constexpr size_t WL2_OFF  = WL1_OFF + 2048 * 4;
static constexpr size_t WS_NEED  = WL2_OFF + 512 * 4;

extern "C" void kernel_launch(void* const* d_in, const int* in_sizes, int n_in,
                              void* d_out, int out_size, void* d_ws, size_t ws_size,
                              hipStream_t stream)
{
    if (ws_size < WS_NEED) return;

    const float* x  = (const float*)d_in[0];
    const float* rw = (const float*)d_in[1];
    const float* rb = (const float*)d_in[2];
    const float* w1 = (const float*)d_in[3];
    const float* b1 = (const float*)d_in[4];
    const float* w2 = (const float*)d_in[5];
    const float* b2 = (const float*)d_in[6];
    float* y = (float*)d_out;

    char* ws = (char*)d_ws;
    unsigned short* xb  = (unsigned short*)(ws + XB_OFF);
    unsigned short* w1b = (unsigned short*)(ws + W1B_OFF);
    unsigned short* w2b = (unsigned short*)(ws + W2B_OFF);
    unsigned short* hg  = (unsigned short*)(ws + HG_OFF);
    int*   rowtok  = (int*)  (ws + RT_OFF);
    float* rowgate = (float*)(ws + RG_OFF);
    int*   tidx    = (int*)  (ws + TI_OFF);
    float* tgate   = (float*)(ws + TG_OFF);
    int*   meta    = (int*)  (ws + META_OFF);
    int*   wl1     = (int*)  (ws + WL1_OFF);
    int*   wl2     = (int*)  (ws + WL2_OFF);
    int* counts  = meta;         // [0..7]
    int* counts2 = meta + 8;     // [8..15]
    int* offsets = meta + 16;    // [16..23]
    int* steal1  = meta + 24;
    int* steal2  = meta + 25;
    int* nits    = meta + 26;    // [26..27]

    hipMemsetAsync(meta, 0, 128, stream);
    hipMemsetAsync(y, 0, (size_t)out_size * 4, stream);

    cvt_kernel<<<2048, 256, 0, stream>>>(w1, w1b, NEXP*HID*DIM/4);
    cvt_kernel<<<2048, 256, 0, stream>>>(w2, w2b, NEXP*DIM*HID/4);

    router_kernel<<<N_TOK, 64, 0, stream>>>(x, rw, rb, xb, tidx, tgate, counts);
    plan_kernel<<<1, 64, 0, stream>>>(counts, offsets, wl1, wl2, nits);
    assign_kernel<<<N_TOK/256, 256, 0, stream>>>(tidx, tgate, offsets, counts2, rowtok, rowgate);

    gemm1_kernel<<<256, 512, 0, stream>>>(xb, w1b, b1, rowtok, counts, offsets,
                                          wl1, nits, steal1, hg);
    gemm2_kernel<<<256, 512, 0, stream>>>(hg, w2b, b2, rowtok, rowgate, counts, offsets,
                                          wl2, nits, steal2, y);
}